// Round 14
// baseline (205.716 us; speedup 1.0000x reference)
//
#include <hip/hip_runtime.h>
#include <cstdint>

#define DEV static __device__ __forceinline__

typedef __bf16 bf16x8 __attribute__((ext_vector_type(8)));
typedef __bf16 bf16x4 __attribute__((ext_vector_type(4)));
typedef short  s16x4  __attribute__((ext_vector_type(4)));
typedef float  f32x4  __attribute__((ext_vector_type(4)));

#define VM_WAIT4 asm volatile("s_waitcnt vmcnt(4)" ::: "memory")
#define VM_WAIT3 asm volatile("s_waitcnt vmcnt(3)" ::: "memory")
#define VM_WAIT0 asm volatile("s_waitcnt vmcnt(0)" ::: "memory")

DEV unsigned short f32_bf16(float f) {
  union { float f; unsigned u; } v; v.f = f;
  unsigned r = v.u + 0x7FFFu + ((v.u >> 16) & 1u);
  return (unsigned short)(r >> 16);
}

DEV void gload16(const void* g, void* lds) {
  __builtin_amdgcn_global_load_lds((__attribute__((address_space(1))) void*)g,
                                   (__attribute__((address_space(3))) void*)lds,
                                   16, 0, 0);
}

DEV float bcast_lane(float v, int srclane) {
  union { float f; int i; } u; u.f = v;
  u.i = __builtin_amdgcn_ds_bpermute(srclane << 2, u.i);
  return u.f;
}

// ---------------- fused prologue: cast + 2x transpose-cast + mask check ----------------
//   [0, 4096)        cast hs fp32 -> hB bf16            (16 MB read)
//   [4096, 4864)     transpose-cast wqkv -> wqT          (12 MB read)
//   [4864, 5120)     transpose-cast wo   -> woT          ( 4 MB read)
//   [5120, 13312)    mask uniformity check -> mflag      (32 MB read)
DEV void transpose_body(const float* __restrict__ W, unsigned short* __restrict__ WT,
                        int K, int N, int k0, int n0, float (*t)[65]) {
  int tn = threadIdx.x & 63, tk = threadIdx.x >> 6;
#pragma unroll
  for (int i = 0; i < 64; i += 4)
    t[tk + i][tn] = W[(size_t)(k0 + tk + i) * N + n0 + tn];
  __syncthreads();
  int k2 = (threadIdx.x & 31) * 2, n = threadIdx.x >> 5;
#pragma unroll
  for (int i = 0; i < 64; i += 8) {
    int nn = n + i;
    unsigned o = (unsigned)f32_bf16(t[k2][nn]) | ((unsigned)f32_bf16(t[k2 + 1][nn]) << 16);
    *(unsigned*)&WT[(size_t)(n0 + nn) * K + k0 + k2] = o;
  }
}

__global__ void __launch_bounds__(256) prologue(const float* __restrict__ hs,
                                                unsigned short* __restrict__ hB,
                                                const float* __restrict__ wqkv,
                                                unsigned short* __restrict__ wqT,
                                                const float* __restrict__ wo,
                                                unsigned short* __restrict__ woT,
                                                const float* __restrict__ mask,
                                                int* __restrict__ flag) {
  __shared__ float t[64][65];
  const int bid = blockIdx.x;
  if (bid < 4096) {
    int i = bid * 256 + threadIdx.x;
    float4 v = ((const float4*)hs)[i];
    uint2 o;
    o.x = (unsigned)f32_bf16(v.x) | ((unsigned)f32_bf16(v.y) << 16);
    o.y = (unsigned)f32_bf16(v.z) | ((unsigned)f32_bf16(v.w) << 16);
    ((uint2*)hB)[i] = o;
  } else if (bid < 4864) {
    int tt = bid - 4096;
    transpose_body(wqkv, wqT, 1024, 3072, (tt & 15) * 64, (tt >> 4) * 64, t);
  } else if (bid < 5120) {
    int tt = bid - 4864;
    transpose_body(wo, woT, 1024, 1024, (tt & 15) * 64, (tt >> 4) * 64, t);
  } else {
    size_t i = ((size_t)(bid - 5120) * 256 + threadIdx.x) * 4;
    float4 v = *(const float4*)(mask + i);
    if (v.x != 1.0f || v.y != 1.0f || v.z != 1.0f || v.w != 1.0f) atomicOr(flag, 1);
  }
}

// ---------------- GEMM body: C[M][N] = A[M][K] * BT[N][K]^T ----------------
// MODE 0 (TRANS): fp32 C via float4. MODE 2: Qb/Kb [b,h,s,d] via TRANS bf16x4, or
// VTb [b,h,d,s] via the original orientation (already bf16x4 along s).
// TRANS = operand-swapped MFMA mfma(bv, af): lane holds C[s = wm+mt*16+l]
// [col = wn+nt*16+quad*4+r] -> fixed row, 4 CONSECUTIVE cols -> one vector store
// per (mt,nt) (the unswapped fragment forced 64 scattered 2B stores per thread).
// 3-buffer 2-ahead counted-vmcnt pipeline (measured neutral; kept, verified).
template <int MODE, int TN, bool TRANS>
DEV void gemm_body(const unsigned short* __restrict__ A,
                   const unsigned short* __restrict__ BT,
                   float* __restrict__ Cout,
                   unsigned short* __restrict__ Qb,
                   unsigned short* __restrict__ Kb,
                   unsigned short* __restrict__ VTb,
                   int bm, int bn, int M, int N, int K,
                   unsigned short* As, unsigned short* Bs) {
  constexpr int NT = TN / 32;
  constexpr int ASZ = 128 * 32, BSZ = TN * 32;
  const int tid = threadIdx.x, wave = tid >> 6, lane = tid & 63;
  const int l = lane & 15, quad = lane >> 4;
  const int wm = (wave & 1) * 64, wn = (wave >> 1) * (TN >> 1);

  const int srowA = wave * 32 + (lane >> 2);
  const int sswzA = ((lane & 3) ^ (srowA & 3)) * 8;
  const int srowB = (TN == 128) ? srowA : (wave * 16 + (lane >> 2));
  const int sswzB = ((lane & 3) ^ (srowB & 3)) * 8;
  const unsigned short* pA = A + (size_t)(bm * 128 + srowA) * K + sswzA;
  const unsigned short* pB = BT + (size_t)(bn * TN + srowB) * K + sswzB;
  const int ldsA0 = (wave * 32) * 32;
  const int ldsA1 = (wave * 32 + 16) * 32;
  const int ldsB0 = (TN == 128 ? wave * 32 : wave * 16) * 32;
  const int ldsB1 = (wave * 32 + 16) * 32;  // TN==128 only

  auto stage = [&](int buf) {
    gload16(pA, &As[buf * ASZ + ldsA0]);
    gload16(pA + (size_t)16 * K, &As[buf * ASZ + ldsA1]);
    gload16(pB, &Bs[buf * BSZ + ldsB0]);
    if (TN == 128) gload16(pB + (size_t)16 * K, &Bs[buf * BSZ + ldsB1]);
    pA += 32; pB += 32;
  };

  f32x4 acc[4][NT];
#pragma unroll
  for (int i = 0; i < 4; i++)
#pragma unroll
    for (int j = 0; j < NT; j++) { f32x4 z = {0.f, 0.f, 0.f, 0.f}; acc[i][j] = z; }

  stage(0);
  stage(1);

  const int nkt = K >> 5;
  for (int kt = 0; kt < nkt; kt++) {
    const int cur = kt % 3;
    if (kt != nkt - 1) {
      if (TN == 128) { VM_WAIT4; } else { VM_WAIT3; }
    } else {
      VM_WAIT0;
    }
    __builtin_amdgcn_s_barrier();
    __builtin_amdgcn_sched_barrier(0);
    if (kt + 2 < nkt) stage((kt + 2) % 3);
    bf16x8 af[4], bv[NT];
#pragma unroll
    for (int mt = 0; mt < 4; mt++) {
      int r = wm + mt * 16 + l;
      af[mt] = *(const bf16x8*)&As[cur * ASZ + r * 32 + ((quad ^ (r & 3)) * 8)];
    }
#pragma unroll
    for (int nt = 0; nt < NT; nt++) {
      int r = wn + nt * 16 + l;
      bv[nt] = *(const bf16x8*)&Bs[cur * BSZ + r * 32 + ((quad ^ (r & 3)) * 8)];
    }
#pragma unroll
    for (int mt = 0; mt < 4; mt++)
#pragma unroll
      for (int nt = 0; nt < NT; nt++) {
        if (TRANS)
          acc[mt][nt] = __builtin_amdgcn_mfma_f32_16x16x32_bf16(bv[nt], af[mt], acc[mt][nt], 0, 0, 0);
        else
          acc[mt][nt] = __builtin_amdgcn_mfma_f32_16x16x32_bf16(af[mt], bv[nt], acc[mt][nt], 0, 0, 0);
      }
  }

  // epilogue
#pragma unroll
  for (int nt = 0; nt < NT; nt++) {
#pragma unroll
    for (int mt = 0; mt < 4; mt++) {
      if (TRANS) {
        const int s = bm * 128 + wm + mt * 16 + l;
        const int col = bn * TN + wn + nt * 16 + quad * 4;
        if (MODE == 0) {
          *(float4*)&Cout[(size_t)s * N + col] = *(float4*)&acc[mt][nt];
        } else {
          const int bb = s >> 11, sl = s & 2047;
          unsigned short* dst = (col < 1024) ? Qb : Kb;
          const int c = col & 1023;
          const size_t off = ((size_t)(bb * 16 + (c >> 6)) * 2048 + sl) * 64 + (c & 63);
          bf16x4 pk;
#pragma unroll
          for (int r = 0; r < 4; r++) pk[r] = (__bf16)acc[mt][nt][r];
          *(bf16x4*)&dst[off] = pk;
        }
      } else {
        // original orientation: lane col fixed, 4 consecutive rows -> VTb [d][s]
        const int col = bn * TN + wn + nt * 16 + l;
        const int row0 = bm * 128 + wm + mt * 16 + quad * 4;
        const int bb = row0 >> 11, s = row0 & 2047;
        const int c = col - 2048;
        // permute s within its 128-block: keep bits 6,5,1,0; bits 3,2 -> 4,3; bit 4 -> 2
        const int sl = s & 127;
        const int snew = (s & ~127) | (sl & 0x63) | ((sl & 0x0C) << 1) | ((sl & 0x10) >> 2);
        const size_t off = ((size_t)(bb * 16 + (c >> 6)) * 64 + (c & 63)) * 2048 + snew;
        bf16x4 pk;
#pragma unroll
        for (int r = 0; r < 4; r++) pk[r] = (__bf16)acc[mt][nt][r];
        *(bf16x4*)&VTb[off] = pk;
      }
    }
  }
}

// MODE 2, single dispatch (32,24): block-uniform branch — bn<16 => Q/K columns
// (TRANS vector-store epilogue); bn>=16 => V columns (original orientation).
__global__ void __launch_bounds__(256) gemm_qkv(const unsigned short* __restrict__ A,
                                                const unsigned short* __restrict__ BT,
                                                unsigned short* __restrict__ Qb,
                                                unsigned short* __restrict__ Kb,
                                                unsigned short* __restrict__ VTb,
                                                int M, int N, int K) {
  __shared__ __align__(16) unsigned short As[3][128 * 32];
  __shared__ __align__(16) unsigned short Bs[3][128 * 32];
  const int bm = blockIdx.x, bn = blockIdx.y;
  if (bn < 16)
    gemm_body<2, 128, true>(A, BT, nullptr, Qb, Kb, VTb, bm, bn, M, N, K, &As[0][0], &Bs[0][0]);
  else
    gemm_body<2, 128, false>(A, BT, nullptr, Qb, Kb, VTb, bm, bn, M, N, K, &As[0][0], &Bs[0][0]);
}

__global__ void __launch_bounds__(256) gemm_out(const unsigned short* __restrict__ A,
                                                const unsigned short* __restrict__ BT,
                                                float* __restrict__ Cout,
                                                int M, int N, int K) {
  __shared__ __align__(16) unsigned short As[3][128 * 32];
  __shared__ __align__(16) unsigned short Bs[3][64 * 32];
  gemm_body<0, 64, true>(A, BT, Cout, nullptr, nullptr, nullptr,
                         blockIdx.x, blockIdx.y, M, N, K, &As[0][0], &Bs[0][0]);
}

// ---------------- fused flash attention, S^T form, P-in-registers, double-buffered ----------------
// RESTRUCTURED: grid 1024 = 32 q-tiles (64 rows) x 32 (b,h); block 256 = 4 waves
// (2 wq x 2 wk), KVBLK = 64. Same 16 waves/CU as before, but 4 blocks/CU with
// 4-wave barrier groups instead of 2 blocks of 8 -> barrier stalls decouple across
// blocks (the measured 29% idle was barrier/dependency stall, not a pipe limit).
// Per-thread register shape is IDENTICAL to the proven 51us kernel (qf[2][2],
// Oa[2][4], pa8[2]) — the thrice-measured spill wall is respected.
// KVBLK=64 splits each 128-s permutation block into contiguous halves (chunks 0-7 /
// 8-15 = shorts 0-63 / 64-127), so V tile staging stays linear and the in-tile
// chunk (wk*4+quad) maps to phys k = wk*32+(j>=4)*16+quad*4+(j&3), matching pa8.
// sat threshold tightens to |d0| >= 192 (non-sat ib+r in [65,447], inside the LUT).
// LDS: 2 x (K 64x64 + V 64x64) = 32KB + 2KB LUT -> 4 blocks/CU.
__global__ void __launch_bounds__(256, 4) attn(const unsigned short* __restrict__ Qb,
                                               const unsigned short* __restrict__ Kb,
                                               const unsigned short* __restrict__ VTb,
                                               const float* __restrict__ mask,
                                               const float* __restrict__ emb,
                                               const int* __restrict__ mflag,
                                               unsigned short* __restrict__ ctx) {
  // two buffers, each: K tile (64x64) at 0, V^T tile (64x64) at +4096 shorts
  __shared__ __align__(16) unsigned short KV[2][8192];
  __shared__ float biasLUT[512];

  const float LOG2E = 1.4426950408889634f;
  const float c1 = 0.125f * LOG2E;
  const float C2 = 10000.0f * LOG2E;
  const int tid = threadIdx.x, wave = tid >> 6, lane = tid & 63;
  const int l = lane & 15, quad = lane >> 4;
  const int wq = wave & 1, wk = wave >> 1;
  const int bh = blockIdx.x & 31, qt = blockIdx.x >> 5;
  const int b = bh >> 4, h = bh & 15;
  const int q0 = qt * 64;

  for (int i = tid; i < 512; i += 256) {
    int rel = i - 256;
    int rp = rel < 0 ? -rel : rel;
    int off = rp < 8 ? rp
                     : 8 + (rp >= 12) + (rp >= 16) + (rp >= 23) + (rp >= 32) +
                           (rp >= 46) + (rp >= 64) + (rp >= 91);
    int bucket = (rel > 0 ? 16 : 0) + off;
    biasLUT[i] = emb[bucket * 16 + h] * LOG2E;
  }
  const float satL = emb[15 * 16 + h] * LOG2E;
  const float satH = emb[31 * 16 + h] * LOG2E;
  const int masked = *mflag;

  const unsigned short* qb  = Qb  + ((size_t)(b * 16 + h) * 2048 + q0) * 64;
  const unsigned short* kb  = Kb  + (size_t)(b * 16 + h) * 2048 * 64;
  const unsigned short* vtb = VTb + (size_t)(b * 16 + h) * 64 * 2048;
  const float* mbase = mask + (size_t)b * 2048 * 2048;

  const int rw8 = lane >> 3, c8s = lane & 7;  // staging: 8 rows x 8 chunks per issue

  // ---- prologue: Q (64x64) -> buf1 K-region, tile0 K/V -> buf0 ----
#pragma unroll
  for (int j = 0; j < 2; j++) {
    int row = wave * 16 + j * 8 + rw8;
    gload16(qb + (size_t)row * 64 + ((c8s ^ (row & 7)) * 8), &KV[1][(wave * 16 + j * 8) * 64]);
  }
#pragma unroll
  for (int j = 0; j < 2; j++) {
    int row = wave * 16 + j * 8 + rw8;
    gload16(kb + (size_t)row * 64 + ((c8s ^ (row & 7)) * 8), &KV[0][(wave * 16 + j * 8) * 64]);
  }
#pragma unroll
  for (int j = 0; j < 2; j++) {
    int drow = wave * 16 + j * 8 + rw8;
    gload16(vtb + (size_t)drow * 2048 + ((c8s ^ (drow & 7)) * 8),
            &KV[0][4096 + (wave * 16 + j * 8) * 64]);
  }
  __syncthreads();

  // each wave reads its 32 Q rows (staged region of buf1)
  bf16x8 qf[2][2];
#pragma unroll
  for (int mtq = 0; mtq < 2; mtq++)
#pragma unroll
    for (int ks = 0; ks < 2; ks++) {
      int row = wq * 32 + mtq * 16 + l;
      qf[mtq][ks] = *(const bf16x8*)&KV[1][row * 64 + (((ks * 4 + quad) ^ (row & 7)) * 8)];
    }
  __syncthreads();  // Q reads complete before buf1 is overwritten with tile1

  // ---- stage tile1 -> buf1 ----
#pragma unroll
  for (int j = 0; j < 2; j++) {
    int row = wave * 16 + j * 8 + rw8;
    gload16(kb + (size_t)(64 + row) * 64 + ((c8s ^ (row & 7)) * 8),
            &KV[1][(wave * 16 + j * 8) * 64]);
  }
#pragma unroll
  for (int j = 0; j < 2; j++) {
    int drow = wave * 16 + j * 8 + rw8;
    gload16(vtb + (size_t)drow * 2048 + 64 + ((c8s ^ (drow & 7)) * 8),
            &KV[1][4096 + (wave * 16 + j * 8) * 64]);
  }

  float lr[2] = {0.f, 0.f};
  f32x4 Oa[2][4];
#pragma unroll
  for (int mtq = 0; mtq < 2; mtq++)
#pragma unroll
    for (int dt = 0; dt < 4; dt++) { f32x4 z = {0.f, 0.f, 0.f, 0.f}; Oa[mtq][dt] = z; }

  for (int kt = 0; kt < 32; kt++) {
    const int k0 = kt * 64;
    const unsigned short* Ks  = KV[kt & 1];
    const unsigned short* VTs = KV[kt & 1] + 4096;

    const int d0 = k0 - q0;
    const bool sat = (d0 >= 192) || (d0 <= -192);
    const float bias_u = d0 > 0 ? satH : satL;
    const int ibase = 256 + d0 + wk * 32 + quad * 4 - wq * 32 - l;

    // ---- S^T for this wave's 32 k-rows (2 slabs), then PV ----
    bf16x8 pa8[2];  // A-fragment for 16x16x32 PV: slots 0-3 from ntk 0, 4-7 from ntk 1
#pragma unroll
    for (int t = 0; t < 2; t++) {
      const int ntk = t;
      int row = wk * 32 + ntk * 16 + l;
      bf16x8 kf0 = *(const bf16x8*)&Ks[row * 64 + ((quad ^ (row & 7)) * 8)];
      bf16x8 kf1 = *(const bf16x8*)&Ks[row * 64 + (((4 + quad) ^ (row & 7)) * 8)];
#pragma unroll
      for (int mtq = 0; mtq < 2; mtq++) {
        f32x4 s = {0.f, 0.f, 0.f, 0.f};
        __builtin_amdgcn_s_setprio(1);
        s = __builtin_amdgcn_mfma_f32_16x16x32_bf16(kf0, qf[mtq][0], s, 0, 0, 0);
        s = __builtin_amdgcn_mfma_f32_16x16x32_bf16(kf1, qf[mtq][1], s, 0, 0, 0);
        __builtin_amdgcn_s_setprio(0);

        const int ib = ibase + ntk * 16 - mtq * 16;
        if (!masked) {
          if (sat) {
#pragma unroll
            for (int r = 0; r < 4; r++) s[r] = fmaf(s[r], c1, bias_u);
          } else {
#pragma unroll
            for (int r = 0; r < 4; r++) s[r] = fmaf(s[r], c1, biasLUT[ib + r]);
          }
        } else {
          const int qg = q0 + wq * 32 + mtq * 16 + l;
          const int kg = k0 + wk * 32 + ntk * 16 + quad * 4;
          float4 mv4 = *(const float4*)&mbase[(size_t)qg * 2048 + kg];
#pragma unroll
          for (int r = 0; r < 4; r++) {
            float mv = r == 0 ? mv4.x : (r == 1 ? mv4.y : (r == 2 ? mv4.z : mv4.w));
            float bias = sat ? bias_u : biasLUT[ib + r];
            s[r] = fmaf(s[r], mv * c1, fmaf(mv, C2, bias - C2));
          }
        }
        float ls = 0.f;
#pragma unroll
        for (int r = 0; r < 4; r++) {
          float pv = __builtin_amdgcn_exp2f(s[r]);  // softmax shift-invariance: no max needed
          ls += pv;
          pa8[mtq][t * 4 + r] = (__bf16)pv;
        }
        lr[mtq] += ls;
      }
    }

    // ---- O += P V: one 16x16x32 MFMA per (dt,mtq); B straight from b128 ----
    __builtin_amdgcn_s_setprio(1);
#pragma unroll
    for (int dt = 0; dt < 4; dt++) {
      int row = dt * 16 + l;
      bf16x8 w = *(const bf16x8*)&VTs[row * 64 + (((wk * 4 + quad) ^ (row & 7)) * 8)];
#pragma unroll
      for (int mtq = 0; mtq < 2; mtq++)
        Oa[mtq][dt] = __builtin_amdgcn_mfma_f32_16x16x32_bf16(pa8[mtq], w, Oa[mtq][dt], 0, 0, 0);
    }
    __builtin_amdgcn_s_setprio(0);

    // ---- one barrier: all reads of this buffer done + next tile's loads landed ----
    __syncthreads();
    if (kt + 2 < 32) {
      const int kn = (kt + 2) * 64;
      unsigned short* dst = (unsigned short*)KV[kt & 1];
#pragma unroll
      for (int j = 0; j < 2; j++) {
        int row = wave * 16 + j * 8 + rw8;
        gload16(kb + (size_t)(kn + row) * 64 + ((c8s ^ (row & 7)) * 8),
                &dst[(wave * 16 + j * 8) * 64]);
      }
#pragma unroll
      for (int j = 0; j < 2; j++) {
        int drow = wave * 16 + j * 8 + rw8;
        gload16(vtb + (size_t)drow * 2048 + kn + ((c8s ^ (drow & 7)) * 8),
                &dst[4096 + (wave * 16 + j * 8) * 64]);
      }
    }
  }

  // ---- cross-wave (wk) reduction through freed KV, then normalize + store ----
  float* Of = (float*)KV;       // 4096 floats = 16KB (q 0..63 x d 0..63)
  float* Lf = Of + 4096;        // 64 floats
  if (wk == 1) {
#pragma unroll
    for (int mtq = 0; mtq < 2; mtq++) {
      float v = lr[mtq];
      v += __shfl_xor(v, 16);
      v += __shfl_xor(v, 32);
      if (quad == 0) Lf[wq * 32 + mtq * 16 + l] = v;
#pragma unroll
      for (int dt = 0; dt < 4; dt++)
#pragma unroll
        for (int r = 0; r < 4; r++)
          Of[(wq * 32 + mtq * 16 + quad * 4 + r) * 64 + dt * 16 + l] = Oa[mtq][dt][r];
    }
  }
  __syncthreads();
  if (wk == 0) {
#pragma unroll
    for (int mtq = 0; mtq < 2; mtq++) {
      float v = lr[mtq];
      v += __shfl_xor(v, 16);
      v += __shfl_xor(v, 32);
      v += Lf[wq * 32 + mtq * 16 + l];
      const float inv = 1.0f / v;
#pragma unroll
      for (int r = 0; r < 4; r++) {
        float i_bc = bcast_lane(inv, quad * 4 + r);
        const int qg = q0 + wq * 32 + mtq * 16 + quad * 4 + r;
#pragma unroll
        for (int dt = 0; dt < 4; dt++) {
          float o = Oa[mtq][dt][r] +
                    Of[(wq * 32 + mtq * 16 + quad * 4 + r) * 64 + dt * 16 + l];
          ctx[(size_t)(b * 2048 + qg) * 1024 + h * 64 + dt * 16 + l] = f32_bf16(o * i_bc);
        }
      }
    }
  }
}

// ---------------- launch ----------------
extern "C" void kernel_launch(void* const* d_in, const int* in_sizes, int n_in,
                              void* d_out, int out_size, void* d_ws, size_t ws_size,
                              hipStream_t stream) {
  const float* hs   = (const float*)d_in[0];
  const float* mask = (const float*)d_in[1];
  const float* wqkv = (const float*)d_in[2];
  const float* wo   = (const float*)d_in[3];
  const float* emb  = (const float*)d_in[4];
  float* out = (float*)d_out;

  char* ws = (char*)d_ws;
  unsigned short* hB  = (unsigned short*)(ws);               //  8 MB (alias ctx)
  unsigned short* ctx = (unsigned short*)(ws);               //  alias
  unsigned short* wqT = (unsigned short*)(ws + 8388608);     //  6 MB
  unsigned short* woT = (unsigned short*)(ws + 14680064);    //  2 MB
  unsigned short* Qb  = (unsigned short*)(ws + 16777216);    //  8 MB  [b,h,s,d]
  unsigned short* Kb  = (unsigned short*)(ws + 25165824);    //  8 MB  [b,h,s,d]
  unsigned short* VTb = (unsigned short*)(ws + 33554432);    //  8 MB  [b,h,d,s] (s-permuted)
  int* mflag          = (int*)(ws + 41943040);
  if (ws_size < 41943044) return;

  hipMemsetAsync(mflag, 0, 4, stream);
  prologue<<<13312, 256, 0, stream>>>(hs, hB, wqkv, wqT, wo, woT, mask, mflag);
  gemm_qkv<<<dim3(32, 24), 256, 0, stream>>>(hB, wqT, Qb, Kb, VTb, 4096, 3072, 1024);
  attn<<<1024, 256, 0, stream>>>(Qb, Kb, VTb, mask, emb, mflag, ctx);
  gemm_out<<<dim3(32, 16), 256, 0, stream>>>(ctx, woT, out, 4096, 1024, 1024);
}

// Round 15
// 200.021 us; speedup vs baseline: 1.0285x; 1.0285x over previous
//
#include <hip/hip_runtime.h>
#include <cstdint>

#define DEV static __device__ __forceinline__

typedef __bf16 bf16x8 __attribute__((ext_vector_type(8)));
typedef __bf16 bf16x4 __attribute__((ext_vector_type(4)));
typedef short  s16x4  __attribute__((ext_vector_type(4)));
typedef float  f32x4  __attribute__((ext_vector_type(4)));

#define VM_WAIT4 asm volatile("s_waitcnt vmcnt(4)" ::: "memory")
#define VM_WAIT3 asm volatile("s_waitcnt vmcnt(3)" ::: "memory")
#define VM_WAIT0 asm volatile("s_waitcnt vmcnt(0)" ::: "memory")

DEV unsigned short f32_bf16(float f) {
  union { float f; unsigned u; } v; v.f = f;
  unsigned r = v.u + 0x7FFFu + ((v.u >> 16) & 1u);
  return (unsigned short)(r >> 16);
}

DEV void gload16(const void* g, void* lds) {
  __builtin_amdgcn_global_load_lds((__attribute__((address_space(1))) void*)g,
                                   (__attribute__((address_space(3))) void*)lds,
                                   16, 0, 0);
}

DEV float bcast_lane(float v, int srclane) {
  union { float f; int i; } u; u.f = v;
  u.i = __builtin_amdgcn_ds_bpermute(srclane << 2, u.i);
  return u.f;
}

// ---------------- fused prologue: cast + 2x transpose-cast + mask check ----------------
//   [0, 4096)        cast hs fp32 -> hB bf16            (16 MB read)
//   [4096, 4864)     transpose-cast wqkv -> wqT          (12 MB read)
//   [4864, 5120)     transpose-cast wo   -> woT          ( 4 MB read)
//   [5120, 13312)    mask uniformity check -> mflag      (32 MB read)
DEV void transpose_body(const float* __restrict__ W, unsigned short* __restrict__ WT,
                        int K, int N, int k0, int n0, float (*t)[65]) {
  int tn = threadIdx.x & 63, tk = threadIdx.x >> 6;
#pragma unroll
  for (int i = 0; i < 64; i += 4)
    t[tk + i][tn] = W[(size_t)(k0 + tk + i) * N + n0 + tn];
  __syncthreads();
  int k2 = (threadIdx.x & 31) * 2, n = threadIdx.x >> 5;
#pragma unroll
  for (int i = 0; i < 64; i += 8) {
    int nn = n + i;
    unsigned o = (unsigned)f32_bf16(t[k2][nn]) | ((unsigned)f32_bf16(t[k2 + 1][nn]) << 16);
    *(unsigned*)&WT[(size_t)(n0 + nn) * K + k0 + k2] = o;
  }
}

__global__ void __launch_bounds__(256) prologue(const float* __restrict__ hs,
                                                unsigned short* __restrict__ hB,
                                                const float* __restrict__ wqkv,
                                                unsigned short* __restrict__ wqT,
                                                const float* __restrict__ wo,
                                                unsigned short* __restrict__ woT,
                                                const float* __restrict__ mask,
                                                int* __restrict__ flag) {
  __shared__ float t[64][65];
  const int bid = blockIdx.x;
  if (bid < 4096) {
    int i = bid * 256 + threadIdx.x;
    float4 v = ((const float4*)hs)[i];
    uint2 o;
    o.x = (unsigned)f32_bf16(v.x) | ((unsigned)f32_bf16(v.y) << 16);
    o.y = (unsigned)f32_bf16(v.z) | ((unsigned)f32_bf16(v.w) << 16);
    ((uint2*)hB)[i] = o;
  } else if (bid < 4864) {
    int tt = bid - 4096;
    transpose_body(wqkv, wqT, 1024, 3072, (tt & 15) * 64, (tt >> 4) * 64, t);
  } else if (bid < 5120) {
    int tt = bid - 4864;
    transpose_body(wo, woT, 1024, 1024, (tt & 15) * 64, (tt >> 4) * 64, t);
  } else {
    size_t i = ((size_t)(bid - 5120) * 256 + threadIdx.x) * 4;
    float4 v = *(const float4*)(mask + i);
    if (v.x != 1.0f || v.y != 1.0f || v.z != 1.0f || v.w != 1.0f) atomicOr(flag, 1);
  }
}

// ---------------- GEMM body: C[M][N] = A[M][K] * BT[N][K]^T ----------------
// MODE 0 (TRANS): fp32 C via float4. MODE 2: Qb/Kb [b,h,s,d] via TRANS bf16x4, or
// VTb [b,h,d,s] via the original orientation (already bf16x4 along s).
// TRANS = operand-swapped MFMA mfma(bv, af): lane holds C[s = wm+mt*16+l]
// [col = wn+nt*16+quad*4+r] -> fixed row, 4 CONSECUTIVE cols -> one vector store
// per (mt,nt) (the unswapped fragment forced 64 scattered 2B stores per thread).
// 3-buffer 2-ahead counted-vmcnt pipeline (measured neutral; kept, verified).
template <int MODE, int TN, bool TRANS>
DEV void gemm_body(const unsigned short* __restrict__ A,
                   const unsigned short* __restrict__ BT,
                   float* __restrict__ Cout,
                   unsigned short* __restrict__ Qb,
                   unsigned short* __restrict__ Kb,
                   unsigned short* __restrict__ VTb,
                   int bm, int bn, int M, int N, int K,
                   unsigned short* As, unsigned short* Bs) {
  constexpr int NT = TN / 32;
  constexpr int ASZ = 128 * 32, BSZ = TN * 32;
  const int tid = threadIdx.x, wave = tid >> 6, lane = tid & 63;
  const int l = lane & 15, quad = lane >> 4;
  const int wm = (wave & 1) * 64, wn = (wave >> 1) * (TN >> 1);

  const int srowA = wave * 32 + (lane >> 2);
  const int sswzA = ((lane & 3) ^ (srowA & 3)) * 8;
  const int srowB = (TN == 128) ? srowA : (wave * 16 + (lane >> 2));
  const int sswzB = ((lane & 3) ^ (srowB & 3)) * 8;
  const unsigned short* pA = A + (size_t)(bm * 128 + srowA) * K + sswzA;
  const unsigned short* pB = BT + (size_t)(bn * TN + srowB) * K + sswzB;
  const int ldsA0 = (wave * 32) * 32;
  const int ldsA1 = (wave * 32 + 16) * 32;
  const int ldsB0 = (TN == 128 ? wave * 32 : wave * 16) * 32;
  const int ldsB1 = (wave * 32 + 16) * 32;  // TN==128 only

  auto stage = [&](int buf) {
    gload16(pA, &As[buf * ASZ + ldsA0]);
    gload16(pA + (size_t)16 * K, &As[buf * ASZ + ldsA1]);
    gload16(pB, &Bs[buf * BSZ + ldsB0]);
    if (TN == 128) gload16(pB + (size_t)16 * K, &Bs[buf * BSZ + ldsB1]);
    pA += 32; pB += 32;
  };

  f32x4 acc[4][NT];
#pragma unroll
  for (int i = 0; i < 4; i++)
#pragma unroll
    for (int j = 0; j < NT; j++) { f32x4 z = {0.f, 0.f, 0.f, 0.f}; acc[i][j] = z; }

  stage(0);
  stage(1);

  const int nkt = K >> 5;
  for (int kt = 0; kt < nkt; kt++) {
    const int cur = kt % 3;
    if (kt != nkt - 1) {
      if (TN == 128) { VM_WAIT4; } else { VM_WAIT3; }
    } else {
      VM_WAIT0;
    }
    __builtin_amdgcn_s_barrier();
    __builtin_amdgcn_sched_barrier(0);
    if (kt + 2 < nkt) stage((kt + 2) % 3);
    bf16x8 af[4], bv[NT];
#pragma unroll
    for (int mt = 0; mt < 4; mt++) {
      int r = wm + mt * 16 + l;
      af[mt] = *(const bf16x8*)&As[cur * ASZ + r * 32 + ((quad ^ (r & 3)) * 8)];
    }
#pragma unroll
    for (int nt = 0; nt < NT; nt++) {
      int r = wn + nt * 16 + l;
      bv[nt] = *(const bf16x8*)&Bs[cur * BSZ + r * 32 + ((quad ^ (r & 3)) * 8)];
    }
#pragma unroll
    for (int mt = 0; mt < 4; mt++)
#pragma unroll
      for (int nt = 0; nt < NT; nt++) {
        if (TRANS)
          acc[mt][nt] = __builtin_amdgcn_mfma_f32_16x16x32_bf16(bv[nt], af[mt], acc[mt][nt], 0, 0, 0);
        else
          acc[mt][nt] = __builtin_amdgcn_mfma_f32_16x16x32_bf16(af[mt], bv[nt], acc[mt][nt], 0, 0, 0);
      }
  }

  // epilogue
#pragma unroll
  for (int nt = 0; nt < NT; nt++) {
#pragma unroll
    for (int mt = 0; mt < 4; mt++) {
      if (TRANS) {
        const int s = bm * 128 + wm + mt * 16 + l;
        const int col = bn * TN + wn + nt * 16 + quad * 4;
        if (MODE == 0) {
          *(float4*)&Cout[(size_t)s * N + col] = *(float4*)&acc[mt][nt];
        } else {
          const int bb = s >> 11, sl = s & 2047;
          unsigned short* dst = (col < 1024) ? Qb : Kb;
          const int c = col & 1023;
          const size_t off = ((size_t)(bb * 16 + (c >> 6)) * 2048 + sl) * 64 + (c & 63);
          bf16x4 pk;
#pragma unroll
          for (int r = 0; r < 4; r++) pk[r] = (__bf16)acc[mt][nt][r];
          *(bf16x4*)&dst[off] = pk;
        }
      } else {
        // original orientation: lane col fixed, 4 consecutive rows -> VTb [d][s]
        const int col = bn * TN + wn + nt * 16 + l;
        const int row0 = bm * 128 + wm + mt * 16 + quad * 4;
        const int bb = row0 >> 11, s = row0 & 2047;
        const int c = col - 2048;
        // permute s within its 128-block: keep bits 6,5,1,0; bits 3,2 -> 4,3; bit 4 -> 2
        const int sl = s & 127;
        const int snew = (s & ~127) | (sl & 0x63) | ((sl & 0x0C) << 1) | ((sl & 0x10) >> 2);
        const size_t off = ((size_t)(bb * 16 + (c >> 6)) * 64 + (c & 63)) * 2048 + snew;
        bf16x4 pk;
#pragma unroll
        for (int r = 0; r < 4; r++) pk[r] = (__bf16)acc[mt][nt][r];
        *(bf16x4*)&VTb[off] = pk;
      }
    }
  }
}

// MODE 2, single dispatch (32,24): block-uniform branch — bn<16 => Q/K columns
// (TRANS vector-store epilogue); bn>=16 => V columns (original orientation).
__global__ void __launch_bounds__(256) gemm_qkv(const unsigned short* __restrict__ A,
                                                const unsigned short* __restrict__ BT,
                                                unsigned short* __restrict__ Qb,
                                                unsigned short* __restrict__ Kb,
                                                unsigned short* __restrict__ VTb,
                                                int M, int N, int K) {
  __shared__ __align__(16) unsigned short As[3][128 * 32];
  __shared__ __align__(16) unsigned short Bs[3][128 * 32];
  const int bm = blockIdx.x, bn = blockIdx.y;
  if (bn < 16)
    gemm_body<2, 128, true>(A, BT, nullptr, Qb, Kb, VTb, bm, bn, M, N, K, &As[0][0], &Bs[0][0]);
  else
    gemm_body<2, 128, false>(A, BT, nullptr, Qb, Kb, VTb, bm, bn, M, N, K, &As[0][0], &Bs[0][0]);
}

__global__ void __launch_bounds__(256) gemm_out(const unsigned short* __restrict__ A,
                                                const unsigned short* __restrict__ BT,
                                                float* __restrict__ Cout,
                                                int M, int N, int K) {
  __shared__ __align__(16) unsigned short As[3][128 * 32];
  __shared__ __align__(16) unsigned short Bs[3][64 * 32];
  gemm_body<0, 64, true>(A, BT, Cout, nullptr, nullptr, nullptr,
                         blockIdx.x, blockIdx.y, M, N, K, &As[0][0], &Bs[0][0]);
}

// ---------------- fused flash attention, S^T form, P-in-registers, double-buffered ----------------
// grid 512 = 16 q-tiles x 32 (b,h); block 512 = 8 waves = 4 wq (32 q-rows) x 2 wk (64 k-rows).
// PROVEN-BEST configuration (attn 51.0us, total 201.1us; reproduced twice).
// Negative results recorded for future sessions: (1) V-direct-from-L2 and biasLUT4
// both spilled — at __launch_bounds__(512,4) any added vector temp in the kt-loop
// exceeds the 64-arch-VGPR budget (+HBM WRITE_SIZE is the tripwire); (2) 64-row
// q-tile / 4-wave blocks: conflicts 9x lower but dur +4.4us (conflicts not on
// critical path; barrier count doubled); (3) T5 setprio neutral (kept, harmless);
// (4) counted-vmcnt GEMM pipeline neutral (LDS-issue-bound, kept).
// PV uses 16x16x32 MFMA: A = concat of two consecutive QK C-fragments (pa8), B = one
// b128 V read (VTb s-permutation makes both operands' k-relabeling identical).
// QK/PV interleaved per ntk-pair keeps pa8 at 8 live VGPRs (pa[2][4] spilled).
// blockIdx decode groups one (b,h)'s q-blocks per XCD (L2 reuse of K/V panels).
// One barrier per kt; tile kt+2 staged into the buffer just consumed.
__global__ void __launch_bounds__(512, 4) attn(const unsigned short* __restrict__ Qb,
                                               const unsigned short* __restrict__ Kb,
                                               const unsigned short* __restrict__ VTb,
                                               const float* __restrict__ mask,
                                               const float* __restrict__ emb,
                                               const int* __restrict__ mflag,
                                               unsigned short* __restrict__ ctx) {
  // two buffers, each: K tile (128x64) + V^T tile (64x128)
  __shared__ __align__(16) unsigned short KV[2][16384];
  __shared__ float biasLUT[512];

  const float LOG2E = 1.4426950408889634f;
  const float c1 = 0.125f * LOG2E;
  const float C2 = 10000.0f * LOG2E;
  const int tid = threadIdx.x, wave = tid >> 6, lane = tid & 63;
  const int l = lane & 15, quad = lane >> 4;
  const int wq = wave & 3, wk = wave >> 2;
  const int bh = blockIdx.x & 31, qt = blockIdx.x >> 5;
  const int b = bh >> 4, h = bh & 15;
  const int q0 = qt * 128;

  {
    int i = tid;  // 512 threads cover the 512-entry LUT exactly once
    int rel = i - 256;
    int rp = rel < 0 ? -rel : rel;
    int off = rp < 8 ? rp
                     : 8 + (rp >= 12) + (rp >= 16) + (rp >= 23) + (rp >= 32) +
                           (rp >= 46) + (rp >= 64) + (rp >= 91);
    int bucket = (rel > 0 ? 16 : 0) + off;
    biasLUT[i] = emb[bucket * 16 + h] * LOG2E;
  }
  const float satL = emb[15 * 16 + h] * LOG2E;
  const float satH = emb[31 * 16 + h] * LOG2E;
  const int masked = *mflag;

  const unsigned short* qb  = Qb  + ((size_t)(b * 16 + h) * 2048 + q0) * 64;
  const unsigned short* kb  = Kb  + (size_t)(b * 16 + h) * 2048 * 64;
  const unsigned short* vtb = VTb + (size_t)(b * 16 + h) * 64 * 2048;
  const float* mbase = mask + (size_t)b * 2048 * 2048;

  const int rw8 = lane >> 3, c8s = lane & 7;    // K/Q staging: 8 chunks/row
  const int rw16 = lane >> 4, c16 = lane & 15;  // V staging: 16 chunks/row

  // ---- prologue: Q -> buf1 K-region, tile0 K/V -> buf0 ----
#pragma unroll
  for (int j = 0; j < 2; j++) {
    int row = wave * 16 + j * 8 + rw8;
    gload16(qb + (size_t)row * 64 + ((c8s ^ (row & 7)) * 8), &KV[1][(wave * 16 + j * 8) * 64]);
  }
#pragma unroll
  for (int j = 0; j < 2; j++) {
    int row = wave * 16 + j * 8 + rw8;
    gload16(kb + (size_t)row * 64 + ((c8s ^ (row & 7)) * 8), &KV[0][(wave * 16 + j * 8) * 64]);
  }
#pragma unroll
  for (int j = 0; j < 2; j++) {
    int drow = wave * 8 + j * 4 + rw16;
    gload16(vtb + (size_t)drow * 2048 + ((c16 ^ (drow & 7)) * 8),
            &KV[0][8192 + (wave * 8 + j * 4) * 128]);
  }
  __syncthreads();

  // each wave reads its 32 Q rows (staged region of buf1)
  bf16x8 qf[2][2];
#pragma unroll
  for (int mtq = 0; mtq < 2; mtq++)
#pragma unroll
    for (int ks = 0; ks < 2; ks++) {
      int row = wq * 32 + mtq * 16 + l;
      qf[mtq][ks] = *(const bf16x8*)&KV[1][row * 64 + (((ks * 4 + quad) ^ (row & 7)) * 8)];
    }
  __syncthreads();  // Q reads complete before buf1 is overwritten with tile1

  // ---- stage tile1 -> buf1 ----
#pragma unroll
  for (int j = 0; j < 2; j++) {
    int row = wave * 16 + j * 8 + rw8;
    gload16(kb + (size_t)(128 + row) * 64 + ((c8s ^ (row & 7)) * 8),
            &KV[1][(wave * 16 + j * 8) * 64]);
  }
#pragma unroll
  for (int j = 0; j < 2; j++) {
    int drow = wave * 8 + j * 4 + rw16;
    gload16(vtb + (size_t)drow * 2048 + 128 + ((c16 ^ (drow & 7)) * 8),
            &KV[1][8192 + (wave * 8 + j * 4) * 128]);
  }

  float lr[2] = {0.f, 0.f};
  f32x4 Oa[2][4];
#pragma unroll
  for (int mtq = 0; mtq < 2; mtq++)
#pragma unroll
    for (int dt = 0; dt < 4; dt++) { f32x4 z = {0.f, 0.f, 0.f, 0.f}; Oa[mtq][dt] = z; }

  for (int kt = 0; kt < 16; kt++) {
    const int k0 = kt * 128;
    const unsigned short* Ks  = KV[kt & 1];
    const unsigned short* VTs = KV[kt & 1] + 8192;

    const int d0 = k0 - q0;
    const bool sat = (d0 >= 256) || (d0 <= -256);
    const float bias_u = d0 > 0 ? satH : satL;
    const int ibase = 256 + d0 + wk * 64 + quad * 4 - wq * 32 - l;

    // ---- interleaved per ntk-pair: S^T (2 k-slabs) then PV for those slabs ----
#pragma unroll
    for (int p = 0; p < 2; p++) {
      bf16x8 pa8[2];  // A-fragment for 16x16x32 PV: slots 0-3 from ntk even, 4-7 odd
#pragma unroll
      for (int t = 0; t < 2; t++) {
        const int ntk = p * 2 + t;
        int row = wk * 64 + ntk * 16 + l;
        bf16x8 kf0 = *(const bf16x8*)&Ks[row * 64 + ((quad ^ (row & 7)) * 8)];
        bf16x8 kf1 = *(const bf16x8*)&Ks[row * 64 + (((4 + quad) ^ (row & 7)) * 8)];
#pragma unroll
        for (int mtq = 0; mtq < 2; mtq++) {
          f32x4 s = {0.f, 0.f, 0.f, 0.f};
          __builtin_amdgcn_s_setprio(1);
          s = __builtin_amdgcn_mfma_f32_16x16x32_bf16(kf0, qf[mtq][0], s, 0, 0, 0);
          s = __builtin_amdgcn_mfma_f32_16x16x32_bf16(kf1, qf[mtq][1], s, 0, 0, 0);
          __builtin_amdgcn_s_setprio(0);

          const int ib = ibase + ntk * 16 - mtq * 16;
          if (!masked) {
            if (sat) {
#pragma unroll
              for (int r = 0; r < 4; r++) s[r] = fmaf(s[r], c1, bias_u);
            } else {
#pragma unroll
              for (int r = 0; r < 4; r++) s[r] = fmaf(s[r], c1, biasLUT[ib + r]);
            }
          } else {
            const int qg = q0 + wq * 32 + mtq * 16 + l;
            const int kg = k0 + wk * 64 + ntk * 16 + quad * 4;
            float4 mv4 = *(const float4*)&mbase[(size_t)qg * 2048 + kg];
#pragma unroll
            for (int r = 0; r < 4; r++) {
              float mv = r == 0 ? mv4.x : (r == 1 ? mv4.y : (r == 2 ? mv4.z : mv4.w));
              float bias = sat ? bias_u : biasLUT[ib + r];
              s[r] = fmaf(s[r], mv * c1, fmaf(mv, C2, bias - C2));
            }
          }
          float ls = 0.f;
#pragma unroll
          for (int r = 0; r < 4; r++) {
            float pv = __builtin_amdgcn_exp2f(s[r]);  // softmax shift-invariance: no max needed
            ls += pv;
            pa8[mtq][t * 4 + r] = (__bf16)pv;
          }
          lr[mtq] += ls;
        }
      }

      // ---- O += P V: one 16x16x32 MFMA per (dt,mtq); B straight from b128 ----
      __builtin_amdgcn_s_setprio(1);
#pragma unroll
      for (int dt = 0; dt < 4; dt++) {
        int row = dt * 16 + l;
        bf16x8 w = *(const bf16x8*)&VTs[row * 128 + (((wk * 8 + p * 4 + quad) ^ (l & 7)) * 8)];
#pragma unroll
        for (int mtq = 0; mtq < 2; mtq++)
          Oa[mtq][dt] = __builtin_amdgcn_mfma_f32_16x16x32_bf16(pa8[mtq], w, Oa[mtq][dt], 0, 0, 0);
      }
      __builtin_amdgcn_s_setprio(0);
    }

    // ---- one barrier: all reads of this buffer done + next tile's loads landed ----
    __syncthreads();
    if (kt + 2 < 16) {
      const int kn = (kt + 2) * 128;
      unsigned short* dst = (unsigned short*)KV[kt & 1];
#pragma unroll
      for (int j = 0; j < 2; j++) {
        int row = wave * 16 + j * 8 + rw8;
        gload16(kb + (size_t)(kn + row) * 64 + ((c8s ^ (row & 7)) * 8),
                &dst[(wave * 16 + j * 8) * 64]);
      }
#pragma unroll
      for (int j = 0; j < 2; j++) {
        int drow = wave * 8 + j * 4 + rw16;
        gload16(vtb + (size_t)drow * 2048 + kn + ((c16 ^ (drow & 7)) * 8),
                &dst[8192 + (wave * 8 + j * 4) * 128]);
      }
    }
  }

  // ---- cross-wave (wk) reduction through freed KV, then normalize + store ----
  float* Of = (float*)KV;       // 8192 floats = 32KB (q 0..127 x d 0..63)
  float* Lf = Of + 8192;        // 128 floats
  if (wk == 1) {
#pragma unroll
    for (int mtq = 0; mtq < 2; mtq++) {
      float v = lr[mtq];
      v += __shfl_xor(v, 16);
      v += __shfl_xor(v, 32);
      if (quad == 0) Lf[wq * 32 + mtq * 16 + l] = v;
#pragma unroll
      for (int dt = 0; dt < 4; dt++)
#pragma unroll
        for (int r = 0; r < 4; r++)
          Of[(wq * 32 + mtq * 16 + quad * 4 + r) * 64 + dt * 16 + l] = Oa[mtq][dt][r];
    }
  }
  __syncthreads();
  if (wk == 0) {
#pragma unroll
    for (int mtq = 0; mtq < 2; mtq++) {
      float v = lr[mtq];
      v += __shfl_xor(v, 16);
      v += __shfl_xor(v, 32);
      v += Lf[wq * 32 + mtq * 16 + l];
      const float inv = 1.0f / v;
#pragma unroll
      for (int r = 0; r < 4; r++) {
        float i_bc = bcast_lane(inv, quad * 4 + r);
        const int qg = q0 + wq * 32 + mtq * 16 + quad * 4 + r;
#pragma unroll
        for (int dt = 0; dt < 4; dt++) {
          float o = Oa[mtq][dt][r] +
                    Of[(wq * 32 + mtq * 16 + quad * 4 + r) * 64 + dt * 16 + l];
          ctx[(size_t)(b * 2048 + qg) * 1024 + h * 64 + dt * 16 + l] = f32_bf16(o * i_bc);
        }
      }
    }
  }
}

// ---------------- launch ----------------
extern "C" void kernel_launch(void* const* d_in, const int* in_sizes, int n_in,
                              void* d_out, int out_size, void* d_ws, size_t ws_size,
                              hipStream_t stream) {
  const float* hs   = (const float*)d_in[0];
  const float* mask = (const float*)d_in[1];
  const float* wqkv = (const float*)d_in[2];
  const float* wo   = (const float*)d_in[3];
  const float* emb  = (const float*)d_in[4];
  float* out = (float*)d_out;

  char* ws = (char*)d_ws;
  unsigned short* hB  = (unsigned short*)(ws);               //  8 MB (alias ctx)
  unsigned short* ctx = (unsigned short*)(ws);               //  alias
  unsigned short* wqT = (unsigned short*)(ws + 8388608);     //  6 MB
  unsigned short* woT = (unsigned short*)(ws + 14680064);    //  2 MB
  unsigned short* Qb  = (unsigned short*)(ws + 16777216);    //  8 MB  [b,h,s,d]
  unsigned short* Kb  = (unsigned short*)(ws + 25165824);    //  8 MB  [b,h,s,d]
  unsigned short* VTb = (unsigned short*)(ws + 33554432);    //  8 MB  [b,h,d,s] (s-permuted)
  int* mflag          = (int*)(ws + 41943040);
  if (ws_size < 41943044) return;

  hipMemsetAsync(mflag, 0, 4, stream);
  prologue<<<13312, 256, 0, stream>>>(hs, hB, wqkv, wqT, wo, woT, mask, mflag);
  gemm_qkv<<<dim3(32, 24), 256, 0, stream>>>(hB, wqT, Qb, Kb, VTb, 4096, 3072, 1024);
  attn<<<512, 512, 0, stream>>>(Qb, Kb, VTb, mask, emb, mflag, ctx);
  gemm_out<<<dim3(32, 16), 256, 0, stream>>>(ctx, woT, out, 4096, 1024, 1024);
}